// Round 3
// baseline (281.837 us; speedup 1.0000x reference)
//
#include <hip/hip_runtime.h>

// Shapes (fixed): B=64 H=16 T=4 Dk=128 Dv=256
#define BH    1024
#define TT    4
#define DK    128
#define DV    256
#define KSEG  8        // k-groups (lanes 0..7 of each wave) — in-wave reduction
#define KLEN  16       // k rows per thread
#define QV    64       // v-cols per block (4 blocks per bh)

// No LDS, no barriers: every thread loads its own k/q fragment from global
// (L1-broadcast across the 16 v-groups), state tile 16 x float4 in VGPRs,
// k-reduction = 3-stage shfl_xor over adjacent lanes. Blocks are pure
// dataflow -> vmcnt queues stay full, no barrier convoys.

#define PH1(idx, kt)                                   \
    { s4[idx].x *= g_; s4[idx].y *= g_;                \
      s4[idx].z *= g_; s4[idx].w *= g_;                \
      kv.x = fmaf(s4[idx].x, (kt), kv.x);              \
      kv.y = fmaf(s4[idx].y, (kt), kv.y);              \
      kv.z = fmaf(s4[idx].z, (kt), kv.z);              \
      kv.w = fmaf(s4[idx].w, (kt), kv.w); }

#define PH2(idx, kt, qt)                               \
    { s4[idx].x = fmaf((kt), d4.x, s4[idx].x);         \
      s4[idx].y = fmaf((kt), d4.y, s4[idx].y);         \
      s4[idx].z = fmaf((kt), d4.z, s4[idx].z);         \
      s4[idx].w = fmaf((kt), d4.w, s4[idx].w);         \
      o4.x = fmaf(s4[idx].x, (qt), o4.x);              \
      o4.y = fmaf(s4[idx].y, (qt), o4.y);              \
      o4.z = fmaf(s4[idx].z, (qt), o4.z);              \
      o4.w = fmaf(s4[idx].w, (qt), o4.w); }

__global__ __launch_bounds__(128, 4)
void delta_rule_kernel(const float* __restrict__ q,
                       const float* __restrict__ k,
                       const float* __restrict__ v,
                       const float* __restrict__ g,
                       const float* __restrict__ beta,
                       const float* __restrict__ s0,
                       float* __restrict__ out)
{
    const int bx      = blockIdx.x;
    const int bh      = bx >> 2;
    const int quarter = bx & 3;
    const int tid     = threadIdx.x;          // 0..127
    const int kg      = tid & (KSEG - 1);     // 0..7  (adjacent lanes, in-wave)
    const int vg      = tid >> 3;             // 0..15
    const int vcol    = quarter * QV + vg * 4;
    const int kr0     = kg * KLEN;

    const float* __restrict__ sin_p = s0 + (size_t)bh * DK * DV;
    float* __restrict__ out_p  = out + (size_t)bh * TT * DV;
    float* __restrict__ sout_p = out + (size_t)BH * TT * DV + (size_t)bh * DK * DV;

    const float* __restrict__ kbase = k    + (size_t)bh * TT * DK;
    const float* __restrict__ qbase = q    + (size_t)bh * TT * DK;
    const float* __restrict__ vbase = v    + (size_t)bh * TT * DV;
    const float* __restrict__ gbase = g    + (size_t)bh * TT;
    const float* __restrict__ bbase = beta + (size_t)bh * TT;

    // g/beta: uniform scalars, load all timesteps up front.
    float gt[TT], bt[TT];
#pragma unroll
    for (int t = 0; t < TT; ++t) {
        gt[t] = __expf(gbase[t]) ;
        bt[t] = bbase[t];
    }

    // State tile: 16 x dwordx4. Wave lanes = 8 kg x 8 vg -> per row-segment
    // 8 x 16B = 128B contiguous (full lines).
    float4 s4[KLEN];
#pragma unroll
    for (int kk = 0; kk < KLEN; ++kk)
        s4[kk] = *(const float4*)&sin_p[(size_t)(kr0 + kk) * DV + vcol];

#pragma unroll
    for (int t = 0; t < TT; ++t) {
        // This thread's k fragment (rows kr0..kr0+15) + its v columns.
        float4 kf0 = *(const float4*)&kbase[t * DK + kr0 +  0];
        float4 kf1 = *(const float4*)&kbase[t * DK + kr0 +  4];
        float4 kf2 = *(const float4*)&kbase[t * DK + kr0 +  8];
        float4 kf3 = *(const float4*)&kbase[t * DK + kr0 + 12];
        float4 v4  = *(const float4*)&vbase[t * DV + vcol];

        const float g_ = gt[t];

        // decay + key-readout partial (4 independent accumulation chains)
        float4 kv = make_float4(0.f, 0.f, 0.f, 0.f);
        PH1( 0, kf0.x) PH1( 1, kf0.y) PH1( 2, kf0.z) PH1( 3, kf0.w)
        PH1( 4, kf1.x) PH1( 5, kf1.y) PH1( 6, kf1.z) PH1( 7, kf1.w)
        PH1( 8, kf2.x) PH1( 9, kf2.y) PH1(10, kf2.z) PH1(11, kf2.w)
        PH1(12, kf3.x) PH1(13, kf3.y) PH1(14, kf3.z) PH1(15, kf3.w)

        // in-wave butterfly over the 8 kg lanes
#pragma unroll
        for (int m = 1; m < KSEG; m <<= 1) {
            kv.x += __shfl_xor(kv.x, m);
            kv.y += __shfl_xor(kv.y, m);
            kv.z += __shfl_xor(kv.z, m);
            kv.w += __shfl_xor(kv.w, m);
        }

        float4 d4;
        d4.x = (v4.x - kv.x) * bt[t];
        d4.y = (v4.y - kv.y) * bt[t];
        d4.z = (v4.z - kv.z) * bt[t];
        d4.w = (v4.w - kv.w) * bt[t];

        // q fragment loaded late to keep live ranges short
        float4 qf0 = *(const float4*)&qbase[t * DK + kr0 +  0];
        float4 qf1 = *(const float4*)&qbase[t * DK + kr0 +  4];
        float4 qf2 = *(const float4*)&qbase[t * DK + kr0 +  8];
        float4 qf3 = *(const float4*)&qbase[t * DK + kr0 + 12];

        // rank-1 update + query-readout partial
        float4 o4 = make_float4(0.f, 0.f, 0.f, 0.f);
        PH2( 0, kf0.x, qf0.x) PH2( 1, kf0.y, qf0.y) PH2( 2, kf0.z, qf0.z) PH2( 3, kf0.w, qf0.w)
        PH2( 4, kf1.x, qf1.x) PH2( 5, kf1.y, qf1.y) PH2( 6, kf1.z, qf1.z) PH2( 7, kf1.w, qf1.w)
        PH2( 8, kf2.x, qf2.x) PH2( 9, kf2.y, qf2.y) PH2(10, kf2.z, qf2.z) PH2(11, kf2.w, qf2.w)
        PH2(12, kf3.x, qf3.x) PH2(13, kf3.y, qf3.y) PH2(14, kf3.z, qf3.z) PH2(15, kf3.w, qf3.w)

#pragma unroll
        for (int m = 1; m < KSEG; m <<= 1) {
            o4.x += __shfl_xor(o4.x, m);
            o4.y += __shfl_xor(o4.y, m);
            o4.z += __shfl_xor(o4.z, m);
            o4.w += __shfl_xor(o4.w, m);
        }
        if (kg == 0)
            *(float4*)&out_p[t * DV + vcol] = o4;
    }

    // Final state write-back: 16 x dwordx4, coalesced.
#pragma unroll
    for (int kk = 0; kk < KLEN; ++kk)
        *(float4*)&sout_p[(size_t)(kr0 + kk) * DV + vcol] = s4[kk];
}

extern "C" void kernel_launch(void* const* d_in, const int* in_sizes, int n_in,
                              void* d_out, int out_size, void* d_ws, size_t ws_size,
                              hipStream_t stream) {
    const float* q    = (const float*)d_in[0];
    const float* k    = (const float*)d_in[1];
    const float* v    = (const float*)d_in[2];
    const float* g    = (const float*)d_in[3];
    const float* beta = (const float*)d_in[4];
    const float* s0   = (const float*)d_in[5];
    float* out = (float*)d_out;

    delta_rule_kernel<<<dim3(BH * 4), dim3(128), 0, stream>>>(q, k, v, g, beta, s0, out);
}

// Round 4
// 270.641 us; speedup vs baseline: 1.0414x; 1.0414x over previous
//
#include <hip/hip_runtime.h>

// Shapes (fixed): B=64 H=16 T=4 Dk=128 Dv=256
#define BH    1024
#define TT    4
#define DK    128
#define DV    256
#define KSEG  8        // k-groups (lanes 0..7 of each wave) — in-wave reduction
#define KLEN  16       // k rows per thread
#define QV    64       // v-cols per block (4 blocks per bh)

// Barrier-free delta-rule step. Thread (kg,vg) owns state tile
// [16*kg..16*kg+15] x [4 cols] as float4 s4[16] held in VGPRs.
// launch_bounds(128,2): VGPR cap 256 so state + pipeline regs NEVER spill.
// t-loop software-pipelined: t+1 k/q/v fragments load during t's compute.
// Block swizzle: all 4 quarter-blocks of a bh share an XCD (bid&1023 = bh,
// 1024 % 8 == 0) so their redundant k/q reads share one L2.

#define PH1(idx, kt)                                   \
    { s4[idx].x *= g_; s4[idx].y *= g_;                \
      s4[idx].z *= g_; s4[idx].w *= g_;                \
      kv.x = fmaf(s4[idx].x, (kt), kv.x);              \
      kv.y = fmaf(s4[idx].y, (kt), kv.y);              \
      kv.z = fmaf(s4[idx].z, (kt), kv.z);              \
      kv.w = fmaf(s4[idx].w, (kt), kv.w); }

#define PH2(idx, kt, qt)                               \
    { s4[idx].x = fmaf((kt), d4.x, s4[idx].x);         \
      s4[idx].y = fmaf((kt), d4.y, s4[idx].y);         \
      s4[idx].z = fmaf((kt), d4.z, s4[idx].z);         \
      s4[idx].w = fmaf((kt), d4.w, s4[idx].w);         \
      o4.x = fmaf(s4[idx].x, (qt), o4.x);              \
      o4.y = fmaf(s4[idx].y, (qt), o4.y);              \
      o4.z = fmaf(s4[idx].z, (qt), o4.z);              \
      o4.w = fmaf(s4[idx].w, (qt), o4.w); }

__global__ __launch_bounds__(128, 2)
void delta_rule_kernel(const float* __restrict__ q,
                       const float* __restrict__ k,
                       const float* __restrict__ v,
                       const float* __restrict__ g,
                       const float* __restrict__ beta,
                       const float* __restrict__ s0,
                       float* __restrict__ out)
{
    const int bx      = blockIdx.x;
    const int bh      = bx & (BH - 1);        // 1024%8==0 -> same XCD for all quarters
    const int quarter = bx >> 10;             // 0..3
    const int tid     = threadIdx.x;          // 0..127
    const int kg      = tid & (KSEG - 1);     // 0..7 (adjacent lanes, in-wave)
    const int vg      = tid >> 3;             // 0..15
    const int vcol    = quarter * QV + vg * 4;
    const int kr0     = kg * KLEN;

    const float* __restrict__ sin_p = s0 + (size_t)bh * DK * DV;
    float* __restrict__ out_p  = out + (size_t)bh * TT * DV;
    float* __restrict__ sout_p = out + (size_t)BH * TT * DV + (size_t)bh * DK * DV;

    const float* __restrict__ kbase = k    + (size_t)bh * TT * DK + kr0;
    const float* __restrict__ qbase = q    + (size_t)bh * TT * DK + kr0;
    const float* __restrict__ vbase = v    + (size_t)bh * TT * DV + vcol;
    const float* __restrict__ gbase = g    + (size_t)bh * TT;
    const float* __restrict__ bbase = beta + (size_t)bh * TT;

    // State tile: 16 x dwordx4 (per wave: 8 x 128B contiguous segments).
    float4 s4[KLEN];
#pragma unroll
    for (int kk = 0; kk < KLEN; ++kk)
        s4[kk] = *(const float4*)&sin_p[(size_t)(kr0 + kk) * DV + vcol];

    // Pipeline registers: current timestep's k/q/v fragments.
    float4 kc0 = *(const float4*)&kbase[ 0];
    float4 kc1 = *(const float4*)&kbase[ 4];
    float4 kc2 = *(const float4*)&kbase[ 8];
    float4 kc3 = *(const float4*)&kbase[12];
    float4 qc0 = *(const float4*)&qbase[ 0];
    float4 qc1 = *(const float4*)&qbase[ 4];
    float4 qc2 = *(const float4*)&qbase[ 8];
    float4 qc3 = *(const float4*)&qbase[12];
    float4 vc  = *(const float4*)&vbase[0];

#pragma unroll
    for (int t = 0; t < TT; ++t) {
        // Prefetch next timestep (folds away at t==TT-1; loads fly during compute).
        float4 kn0, kn1, kn2, kn3, qn0, qn1, qn2, qn3, vn;
        if (t < TT - 1) {
            kn0 = *(const float4*)&kbase[(t + 1) * DK +  0];
            kn1 = *(const float4*)&kbase[(t + 1) * DK +  4];
            kn2 = *(const float4*)&kbase[(t + 1) * DK +  8];
            kn3 = *(const float4*)&kbase[(t + 1) * DK + 12];
            qn0 = *(const float4*)&qbase[(t + 1) * DK +  0];
            qn1 = *(const float4*)&qbase[(t + 1) * DK +  4];
            qn2 = *(const float4*)&qbase[(t + 1) * DK +  8];
            qn3 = *(const float4*)&qbase[(t + 1) * DK + 12];
            vn  = *(const float4*)&vbase[(t + 1) * DV];
        }

        const float g_ = __expf(gbase[t]);   // wave-uniform (scalar path)
        const float bt = bbase[t];

        // decay + key-readout partial (4 independent chains, 16 deep)
        float4 kv = make_float4(0.f, 0.f, 0.f, 0.f);
        PH1( 0, kc0.x) PH1( 1, kc0.y) PH1( 2, kc0.z) PH1( 3, kc0.w)
        PH1( 4, kc1.x) PH1( 5, kc1.y) PH1( 6, kc1.z) PH1( 7, kc1.w)
        PH1( 8, kc2.x) PH1( 9, kc2.y) PH1(10, kc2.z) PH1(11, kc2.w)
        PH1(12, kc3.x) PH1(13, kc3.y) PH1(14, kc3.z) PH1(15, kc3.w)

        // in-wave butterfly over the 8 kg lanes
#pragma unroll
        for (int m = 1; m < KSEG; m <<= 1) {
            kv.x += __shfl_xor(kv.x, m);
            kv.y += __shfl_xor(kv.y, m);
            kv.z += __shfl_xor(kv.z, m);
            kv.w += __shfl_xor(kv.w, m);
        }

        float4 d4;
        d4.x = (vc.x - kv.x) * bt;
        d4.y = (vc.y - kv.y) * bt;
        d4.z = (vc.z - kv.z) * bt;
        d4.w = (vc.w - kv.w) * bt;

        // rank-1 update + query-readout partial
        float4 o4 = make_float4(0.f, 0.f, 0.f, 0.f);
        PH2( 0, kc0.x, qc0.x) PH2( 1, kc0.y, qc0.y) PH2( 2, kc0.z, qc0.z) PH2( 3, kc0.w, qc0.w)
        PH2( 4, kc1.x, qc1.x) PH2( 5, kc1.y, qc1.y) PH2( 6, kc1.z, qc1.z) PH2( 7, kc1.w, qc1.w)
        PH2( 8, kc2.x, qc2.x) PH2( 9, kc2.y, qc2.y) PH2(10, kc2.z, qc2.z) PH2(11, kc2.w, qc2.w)
        PH2(12, kc3.x, qc3.x) PH2(13, kc3.y, qc3.y) PH2(14, kc3.z, qc3.z) PH2(15, kc3.w, qc3.w)

#pragma unroll
        for (int m = 1; m < KSEG; m <<= 1) {
            o4.x += __shfl_xor(o4.x, m);
            o4.y += __shfl_xor(o4.y, m);
            o4.z += __shfl_xor(o4.z, m);
            o4.w += __shfl_xor(o4.w, m);
        }
        if (kg == 0)
            *(float4*)&out_p[t * DV + vcol] = o4;

        // rotate pipeline
        if (t < TT - 1) {
            kc0 = kn0; kc1 = kn1; kc2 = kn2; kc3 = kn3;
            qc0 = qn0; qc1 = qn1; qc2 = qn2; qc3 = qn3;
            vc  = vn;
        }
    }

    // Final state write-back: 16 x dwordx4 (8 x 128B contiguous per wave).
#pragma unroll
    for (int kk = 0; kk < KLEN; ++kk)
        *(float4*)&sout_p[(size_t)(kr0 + kk) * DV + vcol] = s4[kk];
}

extern "C" void kernel_launch(void* const* d_in, const int* in_sizes, int n_in,
                              void* d_out, int out_size, void* d_ws, size_t ws_size,
                              hipStream_t stream) {
    const float* q    = (const float*)d_in[0];
    const float* k    = (const float*)d_in[1];
    const float* v    = (const float*)d_in[2];
    const float* g    = (const float*)d_in[3];
    const float* beta = (const float*)d_in[4];
    const float* s0   = (const float*)d_in[5];
    float* out = (float*)d_out;

    delta_rule_kernel<<<dim3(BH * 4), dim3(128), 0, stream>>>(q, k, v, g, beta, s0, out);
}